// Round 7
// baseline (375.195 us; speedup 1.0000x reference)
//
#include <hip/hip_runtime.h>
#include <hip/hip_bf16.h>
#include <cstdint>

// Problem constants (fixed): B=4, S=2048, E=1024, H=16, HD=64
#define NB 4
#define NS 2048
#define NE 1024
#define NH 16

typedef __attribute__((ext_vector_type(8))) short bf16x8;   // 8 bf16 (4 VGPRs)
typedef __attribute__((ext_vector_type(4))) float f32x4;    // MFMA C/D

__device__ __forceinline__ unsigned short f2bf(float f) {
  unsigned u = __float_as_uint(f);
  u += 0x7fffu + ((u >> 16) & 1u);   // RNE
  return (unsigned short)(u >> 16);
}

// pack two fp32 -> bf16x2 in one b32: +0x8000 round (half-up) + v_perm
__device__ __forceinline__ unsigned pk2bf(float lo, float hi) {
  return __builtin_amdgcn_perm(__float_as_uint(hi) + 0x8000u,
                               __float_as_uint(lo) + 0x8000u, 0x07060302u);
}

__device__ __forceinline__ float exp2_fast(float x) {
#if __has_builtin(__builtin_amdgcn_exp2f)
  return __builtin_amdgcn_exp2f(x);
#else
  float r;
  asm("v_exp_f32 %0, %1" : "=v"(r) : "v"(x));
  return r;
#endif
}

// async global->LDS, 16B/lane. LDS dest = wave-uniform base + lane*16.
__device__ __forceinline__ void gl_lds16(const void* g, void* l) {
  __builtin_amdgcn_global_load_lds(
      (const __attribute__((address_space(1))) void*)g,
      (__attribute__((address_space(3))) void*)l, 16, 0, 0);
}

// ---------------- cast fp32 -> bf16 ----------------
__global__ __launch_bounds__(256) void cast_k(const float* __restrict__ in,
                                              unsigned short* __restrict__ out, int n4) {
  int idx = blockIdx.x * 256 + threadIdx.x;
  if (idx >= n4) return;
  float4 v = ((const float4*)in)[idx];
  ushort4 o;
  o.x = f2bf(v.x); o.y = f2bf(v.y); o.z = f2bf(v.z); o.w = f2bf(v.w);
  ((ushort4*)out)[idx] = o;
}

// ---------------- C = A[M,K] @ B[N,K]^T + bias ----------------
// 128x128 tile, 4 waves 2x2, 4x4 MFMA/wave, BK=64, global_load_lds staging.
// MODE 0: fp32 row-major store (out-proj). MODE 1: split per-head Q/K/VT
// scatter (Q pre-scaled by log2(e)/8 so attention scores are exp2-domain).
template <int MODE>
__global__ __launch_bounds__(256, 2) void gemm_bt(
    const unsigned short* __restrict__ A,   // [M,K] bf16
    const unsigned short* __restrict__ Bm,  // [N,K] bf16
    const float* __restrict__ bias,         // [N] fp32
    void* __restrict__ Cv,                  // MODE0: fp32 [M,N]
    unsigned short* __restrict__ Qp,        // MODE1: [bh][s][64]
    unsigned short* __restrict__ Kp,        // MODE1: [bh][s][64]
    unsigned short* __restrict__ Vp,        // MODE1: [bh][d][s]
    int M, int N, int K) {
  __shared__ __align__(16) unsigned short As[128 * 64];
  __shared__ __align__(16) unsigned short Bs[128 * 64];
  const int tid = threadIdx.x;
  const int lane = tid & 63, wave = tid >> 6;
  const int m0 = blockIdx.y * 128, n0 = blockIdx.x * 128;
  const int wm = (wave >> 1) * 64, wn = (wave & 1) * 64;
  const int fr = lane & 15, fq = lane >> 4;

  f32x4 acc[4][4];
#pragma unroll
  for (int i = 0; i < 4; i++)
#pragma unroll
    for (int j = 0; j < 4; j++) acc[i][j] = (f32x4){0.f, 0.f, 0.f, 0.f};

  const int srow = lane >> 3;                   // 0..7 within 8-row chunk
  const int scol = ((lane & 7) ^ srow) * 8;     // swizzled global col (elems)

  for (int kt = 0; kt < K; kt += 64) {
    __syncthreads();
#pragma unroll
    for (int c = 0; c < 4; c++) {
      const int chunk = wave * 4 + c;           // 0..15, 8 rows each
      const int row = chunk * 8 + srow;
      gl_lds16(A + (size_t)(m0 + row) * K + kt + scol, As + chunk * 512);
      gl_lds16(Bm + (size_t)(n0 + row) * K + kt + scol, Bs + chunk * 512);
    }
    __syncthreads();
#pragma unroll
    for (int s = 0; s < 2; s++) {
      bf16x8 af[4], bf[4];
#pragma unroll
      for (int i = 0; i < 4; i++)
        af[i] = *(const bf16x8*)(As + (wm + i * 16 + fr) * 64 +
                                 (((s * 4 + fq) ^ (fr & 7)) * 8));
#pragma unroll
      for (int j = 0; j < 4; j++)
        bf[j] = *(const bf16x8*)(Bs + (wn + j * 16 + fr) * 64 +
                                 (((s * 4 + fq) ^ (fr & 7)) * 8));
#pragma unroll
      for (int i = 0; i < 4; i++)
#pragma unroll
        for (int j = 0; j < 4; j++)
          acc[i][j] = __builtin_amdgcn_mfma_f32_16x16x32_bf16(af[i], bf[j], acc[i][j], 0, 0, 0);
    }
  }

#pragma unroll
  for (int j = 0; j < 4; j++) {
    const int col = n0 + wn + j * 16 + fr;
    const float bval = bias[col];
    const int h = col / 192, rr = col - h * 192;  // MODE1 only
#pragma unroll
    for (int i = 0; i < 4; i++)
#pragma unroll
      for (int r = 0; r < 4; r++) {
        const int row = m0 + wm + i * 16 + fq * 4 + r;
        float v = acc[i][j][r] + bval;
        if (MODE == 0) {
          ((float*)Cv)[(size_t)row * N + col] = v;
        } else {
          const int b = row >> 11, s = row & 2047;
          const int bh = b * 16 + h;
          if (rr < 64) {          // Q, pre-scaled into exp2 domain
            Qp[((size_t)bh * 2048 + s) * 64 + rr] = f2bf(v * 0.1803368802f);
          } else if (rr < 128) {  // K
            Kp[((size_t)bh * 2048 + s) * 64 + (rr - 64)] = f2bf(v);
          } else {                // V transposed [d][s]
            Vp[((size_t)bh * 64 + (rr - 128)) * 2048 + s] = f2bf(v);
          }
        }
      }
  }
}

// ---------------- MFMA causal flash attention, S^T orientation ----------------
// Q [bh][s][64] (scaled by log2e/8), K [bh][s][64], VT [bh][d][s].
// S^T = K x Q^T; online softmax per q = in-lane 16 keys + 2 shuffles.
// One q-tile (128 q) per block; grid (16,64) = 1024 blocks so the runtime can
// co-schedule ~4 blocks/CU (R5 was grid-limited to 2). launch_bounds(256,2)
// keeps R5's register allocation — R6's (256,4) caused scratch spills
// (VGPR 84->64, WRITE_SIZE 16->158MB).
#define LDK 72   // 144B rows: 16B-aligned
#define LDP 72
__global__ __launch_bounds__(256, 2) void attn_k(
    const unsigned short* __restrict__ Qg, const unsigned short* __restrict__ Kg,
    const unsigned short* __restrict__ Vg, unsigned short* __restrict__ outa) {
  __shared__ __align__(16) unsigned short Ks[64 * LDK];     // [key][d]
  __shared__ __align__(16) unsigned short VTs[64 * LDK];    // [d][key]
  __shared__ __align__(16) unsigned short Ps[4 * 32 * LDP]; // per-wave [q][key]
  const int tid = threadIdx.x;
  const int lane = tid & 63, wave = tid >> 6;
  const int fc = lane & 15, fq = lane >> 4;
  const int bh = blockIdx.y;
  const int b = bh >> 4, h = bh & 15;
  const int kr = tid >> 3, kc = (tid & 7) * 8;   // 8 lanes/row, rows kr, kr+32
  const unsigned short* Qb = Qg + (size_t)bh * 2048 * 64;
  const unsigned short* Kb = Kg + (size_t)bh * 2048 * 64;
  const unsigned short* Vb = Vg + (size_t)bh * 64 * 2048;
  unsigned short* Pw = Ps + wave * 32 * LDP;

  const int qt = 15 - (int)blockIdx.x;   // heavy q-tiles dispatch first
  const int qw = qt * 128 + wave * 32;

  // Q B-frags: qb[g][s] = Q[qw+g*16+fc][s*32 + fq*8 + j]
  bf16x8 qb[2][2];
#pragma unroll
  for (int g = 0; g < 2; g++) {
    const unsigned short* qrow = Qb + (size_t)(qw + g * 16 + fc) * 64;
    qb[g][0] = *(const bf16x8*)(qrow + fq * 8);
    qb[g][1] = *(const bf16x8*)(qrow + 32 + fq * 8);
  }

  f32x4 O[4][2];
#pragma unroll
  for (int dt = 0; dt < 4; dt++)
#pragma unroll
    for (int g = 0; g < 2; g++) O[dt][g] = (f32x4){0.f, 0.f, 0.f, 0.f};
  float msx[2] = {-3e38f, -3e38f}, lsx[2] = {0.f, 0.f};

  const int nkt = qt * 2 + 2;
  uint4 kreg[2], vreg[2];
#pragma unroll
  for (int it = 0; it < 2; it++) {
    kreg[it] = *(const uint4*)(Kb + (size_t)(kr + it * 32) * 64 + kc);
    vreg[it] = *(const uint4*)(Vb + (size_t)(kr + it * 32) * 2048 + kc);
  }

#pragma unroll 1
  for (int kb = 0; kb < nkt; kb++) {
    const int k0 = kb * 64;
    __syncthreads();
#pragma unroll
    for (int it = 0; it < 2; it++) {
      *(uint4*)(Ks + (kr + it * 32) * LDK + kc) = kreg[it];
      *(uint4*)(VTs + (kr + it * 32) * LDK + kc) = vreg[it];
    }
    __syncthreads();
    if (kb + 1 < nkt) {  // prefetch next tile (in flight across compute)
#pragma unroll
      for (int it = 0; it < 2; it++) {
        kreg[it] = *(const uint4*)(Kb + (size_t)(k0 + 64 + kr + it * 32) * 64 + kc);
        vreg[it] = *(const uint4*)(Vb + (size_t)(kr + it * 32) * 2048 + (k0 + 64) + kc);
      }
    }

    if (k0 <= qw + 31) {  // wave-uniform: skip fully-masked tiles
      // S^T tiles: row=key=k0+t*16+fq*4+r, col=q=qw+g*16+fc (exp2 domain)
      f32x4 S[4][2];
#pragma unroll
      for (int t = 0; t < 4; t++) {
        bf16x8 ka0 = *(const bf16x8*)(Ks + (t * 16 + fc) * LDK + fq * 8);
        bf16x8 ka1 = *(const bf16x8*)(Ks + (t * 16 + fc) * LDK + 32 + fq * 8);
#pragma unroll
        for (int g = 0; g < 2; g++) {
          f32x4 s = (f32x4){0.f, 0.f, 0.f, 0.f};
          s = __builtin_amdgcn_mfma_f32_16x16x32_bf16(ka0, qb[g][0], s, 0, 0, 0);
          s = __builtin_amdgcn_mfma_f32_16x16x32_bf16(ka1, qb[g][1], s, 0, 0, 0);
          S[t][g] = s;
        }
      }
      if (k0 + 63 > qw) {  // diagonal tiles only
#pragma unroll
        for (int t = 0; t < 4; t++)
#pragma unroll
          for (int g = 0; g < 2; g++)
#pragma unroll
            for (int r = 0; r < 4; r++)
              if (k0 + t * 16 + fq * 4 + r > qw + g * 16 + fc) S[t][g][r] = -3e38f;
      }
      // online softmax per q: 16 keys in-lane + xor16/xor32 shuffles
      float alpha[2];
#pragma unroll
      for (int g = 0; g < 2; g++) {
        float cm = S[0][g][0];
#pragma unroll
        for (int t = 0; t < 4; t++)
#pragma unroll
          for (int r = 0; r < 4; r++) cm = fmaxf(cm, S[t][g][r]);
        cm = fmaxf(cm, __shfl_xor(cm, 16, 64));
        cm = fmaxf(cm, __shfl_xor(cm, 32, 64));
        float mn = fmaxf(msx[g], cm);
        alpha[g] = exp2_fast(msx[g] - mn);
        msx[g] = mn;
        float ps = 0.f;
#pragma unroll
        for (int t = 0; t < 4; t++)
#pragma unroll
          for (int r = 0; r < 4; r++) {
            float p = exp2_fast(S[t][g][r] - mn);
            S[t][g][r] = p;
            ps += p;
          }
        ps += __shfl_xor(ps, 16, 64);
        ps += __shfl_xor(ps, 32, 64);
        lsx[g] = lsx[g] * alpha[g] + ps;
      }
      // P store [q][key]: perm-packed pairs, b64 per (g,t)
#pragma unroll
      for (int g = 0; g < 2; g++)
#pragma unroll
        for (int t = 0; t < 4; t++) {
          uint2 u;
          u.x = pk2bf(S[t][g][0], S[t][g][1]);
          u.y = pk2bf(S[t][g][2], S[t][g][3]);
          *(uint2*)(Pw + (g * 16 + fc) * LDP + t * 16 + fq * 4) = u;
        }
      bf16x8 pb[2][2];
#pragma unroll
      for (int g = 0; g < 2; g++)
#pragma unroll
        for (int s = 0; s < 2; s++)
          pb[g][s] = *(const bf16x8*)(Pw + (g * 16 + fc) * LDP + s * 32 + fq * 8);
      // rescale O, then O^T += V^T x P
#pragma unroll
      for (int dt = 0; dt < 4; dt++)
#pragma unroll
        for (int g = 0; g < 2; g++)
#pragma unroll
          for (int r = 0; r < 4; r++) O[dt][g][r] *= alpha[g];
#pragma unroll
      for (int dt = 0; dt < 4; dt++) {
        bf16x8 va0 = *(const bf16x8*)(VTs + (dt * 16 + fc) * LDK + fq * 8);
        bf16x8 va1 = *(const bf16x8*)(VTs + (dt * 16 + fc) * LDK + 32 + fq * 8);
#pragma unroll
        for (int g = 0; g < 2; g++) {
          O[dt][g] = __builtin_amdgcn_mfma_f32_16x16x32_bf16(va0, pb[g][0], O[dt][g], 0, 0, 0);
          O[dt][g] = __builtin_amdgcn_mfma_f32_16x16x32_bf16(va1, pb[g][1], O[dt][g], 0, 0, 0);
        }
      }
    }
  }

  // epilogue: lane holds O^T[d=dt*16+fq*4+r][q=g*16+fc]
  float inv[2] = {1.f / lsx[0], 1.f / lsx[1]};
#pragma unroll
  for (int dt = 0; dt < 4; dt++)
#pragma unroll
    for (int g = 0; g < 2; g++) {
      uint2 u;
      u.x = pk2bf(O[dt][g][0] * inv[g], O[dt][g][1] * inv[g]);
      u.y = pk2bf(O[dt][g][2] * inv[g], O[dt][g][3] * inv[g]);
      size_t row = (size_t)(b * NS) + qw + g * 16 + fc;
      *(uint2*)(outa + row * 1024 + h * 64 + dt * 16 + fq * 4) = u;
    }
}

// ---------------- launch ----------------
// ws (bf16 elems): xb[8192*1024] | wqkv[3072*1024] | wo[1024*1024]
//                  | Q[64*2048*64] | K[64*2048*64] | VT[64*64*2048] | att[8192*1024]
extern "C" void kernel_launch(void* const* d_in, const int* in_sizes, int n_in,
                              void* d_out, int out_size, void* d_ws, size_t ws_size,
                              hipStream_t stream) {
  const float* x     = (const float*)d_in[0];
  const float* qkv_w = (const float*)d_in[1];
  const float* qkv_b = (const float*)d_in[2];
  const float* out_w = (const float*)d_in[3];
  const float* out_b = (const float*)d_in[4];

  unsigned short* xb   = (unsigned short*)d_ws;
  unsigned short* wqkv = xb + (size_t)8192 * 1024;
  unsigned short* wo   = wqkv + (size_t)3072 * 1024;
  unsigned short* Qg   = wo + (size_t)1024 * 1024;
  unsigned short* Kg   = Qg + (size_t)64 * 2048 * 64;
  unsigned short* Vg   = Kg + (size_t)64 * 2048 * 64;
  unsigned short* att  = Vg + (size_t)64 * 64 * 2048;

  cast_k<<<(2097152 + 255) / 256, 256, 0, stream>>>(x, xb, 2097152);
  cast_k<<<(786432 + 255) / 256, 256, 0, stream>>>(qkv_w, wqkv, 786432);
  cast_k<<<(262144 + 255) / 256, 256, 0, stream>>>(out_w, wo, 262144);

  gemm_bt<1><<<dim3(24, 64), 256, 0, stream>>>(xb, wqkv, qkv_b, nullptr,
                                               Qg, Kg, Vg, 8192, 3072, 1024);
  attn_k<<<dim3(16, 64), 256, 0, stream>>>(Qg, Kg, Vg, att);
  gemm_bt<0><<<dim3(8, 64), 256, 0, stream>>>(att, wo, out_b, d_out,
                                              nullptr, nullptr, nullptr,
                                              8192, 1024, 1024);
}

// Round 8
// 273.871 us; speedup vs baseline: 1.3700x; 1.3700x over previous
//
#include <hip/hip_runtime.h>
#include <hip/hip_bf16.h>
#include <cstdint>

// Problem constants (fixed): B=4, S=2048, E=1024, H=16, HD=64
#define NB 4
#define NS 2048
#define NE 1024
#define NH 16

typedef __attribute__((ext_vector_type(8))) short bf16x8;   // 8 bf16 (4 VGPRs)
typedef __attribute__((ext_vector_type(4))) float f32x4;    // MFMA C/D

__device__ __forceinline__ unsigned short f2bf(float f) {
  unsigned u = __float_as_uint(f);
  u += 0x7fffu + ((u >> 16) & 1u);   // RNE
  return (unsigned short)(u >> 16);
}

// pack two fp32 -> bf16x2 in one b32: +0x8000 round (half-up) + v_perm
__device__ __forceinline__ unsigned pk2bf(float lo, float hi) {
  return __builtin_amdgcn_perm(__float_as_uint(hi) + 0x8000u,
                               __float_as_uint(lo) + 0x8000u, 0x07060302u);
}

__device__ __forceinline__ float exp2_fast(float x) {
#if __has_builtin(__builtin_amdgcn_exp2f)
  return __builtin_amdgcn_exp2f(x);
#else
  float r;
  asm("v_exp_f32 %0, %1" : "=v"(r) : "v"(x));
  return r;
#endif
}

// async global->LDS, 16B/lane. LDS dest = wave-uniform base + lane*16.
__device__ __forceinline__ void gl_lds16(const void* g, void* l) {
  __builtin_amdgcn_global_load_lds(
      (const __attribute__((address_space(1))) void*)g,
      (__attribute__((address_space(3))) void*)l, 16, 0, 0);
}

// ---------------- cast fp32 -> bf16 ----------------
__global__ __launch_bounds__(256) void cast_k(const float* __restrict__ in,
                                              unsigned short* __restrict__ out, int n4) {
  int idx = blockIdx.x * 256 + threadIdx.x;
  if (idx >= n4) return;
  float4 v = ((const float4*)in)[idx];
  ushort4 o;
  o.x = f2bf(v.x); o.y = f2bf(v.y); o.z = f2bf(v.z); o.w = f2bf(v.w);
  ((ushort4*)out)[idx] = o;
}

// ---------------- C = A[M,K] @ B[N,K]^T + bias ----------------
// 128x128 tile, 4 waves 2x2, 4x4 MFMA/wave, BK=64, global_load_lds staging.
// MODE 0: fp32 row-major store (out-proj). MODE 1: split per-head Q/K/VT
// scatter (Q pre-scaled by log2(e)/8 so attention scores are exp2-domain).
template <int MODE>
__global__ __launch_bounds__(256, 2) void gemm_bt(
    const unsigned short* __restrict__ A,   // [M,K] bf16
    const unsigned short* __restrict__ Bm,  // [N,K] bf16
    const float* __restrict__ bias,         // [N] fp32
    void* __restrict__ Cv,                  // MODE0: fp32 [M,N]
    unsigned short* __restrict__ Qp,        // MODE1: [bh][s][64]
    unsigned short* __restrict__ Kp,        // MODE1: [bh][s][64]
    unsigned short* __restrict__ Vp,        // MODE1: [bh][d][s]
    int M, int N, int K) {
  __shared__ __align__(16) unsigned short As[128 * 64];
  __shared__ __align__(16) unsigned short Bs[128 * 64];
  const int tid = threadIdx.x;
  const int lane = tid & 63, wave = tid >> 6;
  const int m0 = blockIdx.y * 128, n0 = blockIdx.x * 128;
  const int wm = (wave >> 1) * 64, wn = (wave & 1) * 64;
  const int fr = lane & 15, fq = lane >> 4;

  f32x4 acc[4][4];
#pragma unroll
  for (int i = 0; i < 4; i++)
#pragma unroll
    for (int j = 0; j < 4; j++) acc[i][j] = (f32x4){0.f, 0.f, 0.f, 0.f};

  const int srow = lane >> 3;                   // 0..7 within 8-row chunk
  const int scol = ((lane & 7) ^ srow) * 8;     // swizzled global col (elems)

  for (int kt = 0; kt < K; kt += 64) {
    __syncthreads();
#pragma unroll
    for (int c = 0; c < 4; c++) {
      const int chunk = wave * 4 + c;           // 0..15, 8 rows each
      const int row = chunk * 8 + srow;
      gl_lds16(A + (size_t)(m0 + row) * K + kt + scol, As + chunk * 512);
      gl_lds16(Bm + (size_t)(n0 + row) * K + kt + scol, Bs + chunk * 512);
    }
    __syncthreads();
#pragma unroll
    for (int s = 0; s < 2; s++) {
      bf16x8 af[4], bf[4];
#pragma unroll
      for (int i = 0; i < 4; i++)
        af[i] = *(const bf16x8*)(As + (wm + i * 16 + fr) * 64 +
                                 (((s * 4 + fq) ^ (fr & 7)) * 8));
#pragma unroll
      for (int j = 0; j < 4; j++)
        bf[j] = *(const bf16x8*)(Bs + (wn + j * 16 + fr) * 64 +
                                 (((s * 4 + fq) ^ (fr & 7)) * 8));
#pragma unroll
      for (int i = 0; i < 4; i++)
#pragma unroll
        for (int j = 0; j < 4; j++)
          acc[i][j] = __builtin_amdgcn_mfma_f32_16x16x32_bf16(af[i], bf[j], acc[i][j], 0, 0, 0);
    }
  }

#pragma unroll
  for (int j = 0; j < 4; j++) {
    const int col = n0 + wn + j * 16 + fr;
    const float bval = bias[col];
    const int h = col / 192, rr = col - h * 192;  // MODE1 only
#pragma unroll
    for (int i = 0; i < 4; i++)
#pragma unroll
      for (int r = 0; r < 4; r++) {
        const int row = m0 + wm + i * 16 + fq * 4 + r;
        float v = acc[i][j][r] + bval;
        if (MODE == 0) {
          ((float*)Cv)[(size_t)row * N + col] = v;
        } else {
          const int b = row >> 11, s = row & 2047;
          const int bh = b * 16 + h;
          if (rr < 64) {          // Q, pre-scaled into exp2 domain
            Qp[((size_t)bh * 2048 + s) * 64 + rr] = f2bf(v * 0.1803368802f);
          } else if (rr < 128) {  // K
            Kp[((size_t)bh * 2048 + s) * 64 + (rr - 64)] = f2bf(v);
          } else {                // V transposed [d][s]
            Vp[((size_t)bh * 64 + (rr - 128)) * 2048 + s] = f2bf(v);
          }
        }
      }
  }
}

// ---------------- MFMA causal flash attention, S^T orientation ----------------
// Q [bh][s][64] (scaled by log2e/8), K [bh][s][64], VT [bh][d][s].
// S^T = K x Q^T; online softmax per q = in-lane 16 keys + 2 shuffles.
// Block = 2 waves = 64 q; q-tiles PAIRED (qt, 31-qt) -> 1024 uniform blocks
// (33 key-tiles each), 4 resident blocks/CU (25.6KB LDS) -> 4-way overlap of
// the per-tile serial chain (R7 PM: imbalance + resident-grid tail killed
// occupancy; R4-R7 register prefetch caused scratch spills - both removed).
// K/V staged via global_load_lds w16 with XOR-8 chunk swizzle (m97 pattern).
#define LDP 72
__global__ __launch_bounds__(128, 2) void attn_k(
    const unsigned short* __restrict__ Qg, const unsigned short* __restrict__ Kg,
    const unsigned short* __restrict__ Vg, unsigned short* __restrict__ outa) {
  __shared__ __align__(16) unsigned short Ks[64 * 64];      // [key][d] swizzled
  __shared__ __align__(16) unsigned short VTs[64 * 64];     // [d][key] swizzled
  __shared__ __align__(16) unsigned short Ps[2 * 32 * LDP]; // per-wave [q][key]
  const int tid = threadIdx.x;
  const int lane = tid & 63, wave = tid >> 6;
  const int fc = lane & 15, fq = lane >> 4, fc7 = fc & 7;
  const int bh = blockIdx.y;
  const int b = bh >> 4, h = bh & 15;
  const int srow = lane >> 3;                   // 0..7 within 8-row chunk
  const int scol = ((lane & 7) ^ srow) * 8;     // swizzled global col (elems)
  const unsigned short* Qb = Qg + (size_t)bh * 2048 * 64;
  const unsigned short* Kb = Kg + (size_t)bh * 2048 * 64;
  const unsigned short* Vb = Vg + (size_t)bh * 64 * 2048;
  unsigned short* Pw = Ps + wave * 32 * LDP;

#pragma unroll 1
  for (int phase = 0; phase < 2; phase++) {
    const int qt = phase ? 31 - (int)blockIdx.x : (int)blockIdx.x;  // pair: 33 tiles total
    const int qw = qt * 64 + wave * 32;

    // Q B-frags: qb[g][s] = Q[qw+g*16+fc][s*32 + fq*8 + j]
    bf16x8 qb[2][2];
#pragma unroll
    for (int g = 0; g < 2; g++) {
      const unsigned short* qrow = Qb + (size_t)(qw + g * 16 + fc) * 64;
      qb[g][0] = *(const bf16x8*)(qrow + fq * 8);
      qb[g][1] = *(const bf16x8*)(qrow + 32 + fq * 8);
    }

    f32x4 O[4][2];
#pragma unroll
    for (int dt = 0; dt < 4; dt++)
#pragma unroll
      for (int g = 0; g < 2; g++) O[dt][g] = (f32x4){0.f, 0.f, 0.f, 0.f};
    float msx[2] = {-3e38f, -3e38f}, lsx[2] = {0.f, 0.f};

#pragma unroll 1
    for (int kb = 0; kb <= qt; kb++) {
      const int k0 = kb * 64;
      __syncthreads();
      // stage K[64key x 64d] and VT[64d x 64key] via async direct-to-LDS;
      // 4 chunks of 16 rows (2 waves x 8 rows), global col XOR-swizzled.
#pragma unroll
      for (int c = 0; c < 4; c++) {
        const int rbase = c * 16 + wave * 8;
        gl_lds16(Kb + (size_t)(k0 + rbase + srow) * 64 + scol, Ks + rbase * 64);
        gl_lds16(Vb + (size_t)(rbase + srow) * 2048 + k0 + scol, VTs + rbase * 64);
      }
      __syncthreads();

      // S^T tiles: row=key=k0+t*16+fq*4+r, col=q=qw+g*16+fc (exp2 domain)
      f32x4 S[4][2];
#pragma unroll
      for (int t = 0; t < 4; t++) {
        bf16x8 ka0 = *(const bf16x8*)(Ks + (t * 16 + fc) * 64 + ((fq ^ fc7) * 8));
        bf16x8 ka1 = *(const bf16x8*)(Ks + (t * 16 + fc) * 64 + (((4 + fq) ^ fc7) * 8));
#pragma unroll
        for (int g = 0; g < 2; g++) {
          f32x4 s = (f32x4){0.f, 0.f, 0.f, 0.f};
          s = __builtin_amdgcn_mfma_f32_16x16x32_bf16(ka0, qb[g][0], s, 0, 0, 0);
          s = __builtin_amdgcn_mfma_f32_16x16x32_bf16(ka1, qb[g][1], s, 0, 0, 0);
          S[t][g] = s;
        }
      }
      if (kb == qt) {  // diagonal tile: causal mask (wave-uniform branch)
#pragma unroll
        for (int t = 0; t < 4; t++)
#pragma unroll
          for (int g = 0; g < 2; g++)
#pragma unroll
            for (int r = 0; r < 4; r++)
              if (k0 + t * 16 + fq * 4 + r > qw + g * 16 + fc) S[t][g][r] = -3e38f;
      }
      // online softmax per q: 16 keys in-lane + xor16/xor32 shuffles
      float alpha[2];
#pragma unroll
      for (int g = 0; g < 2; g++) {
        float cm = S[0][g][0];
#pragma unroll
        for (int t = 0; t < 4; t++)
#pragma unroll
          for (int r = 0; r < 4; r++) cm = fmaxf(cm, S[t][g][r]);
        cm = fmaxf(cm, __shfl_xor(cm, 16, 64));
        cm = fmaxf(cm, __shfl_xor(cm, 32, 64));
        float mn = fmaxf(msx[g], cm);
        alpha[g] = exp2_fast(msx[g] - mn);
        msx[g] = mn;
        float ps = 0.f;
#pragma unroll
        for (int t = 0; t < 4; t++)
#pragma unroll
          for (int r = 0; r < 4; r++) {
            float p = exp2_fast(S[t][g][r] - mn);
            S[t][g][r] = p;
            ps += p;
          }
        ps += __shfl_xor(ps, 16, 64);
        ps += __shfl_xor(ps, 32, 64);
        lsx[g] = lsx[g] * alpha[g] + ps;
      }
      // P store [q][key]: perm-packed pairs, b64 per (g,t) (per-wave buffer)
#pragma unroll
      for (int g = 0; g < 2; g++)
#pragma unroll
        for (int t = 0; t < 4; t++) {
          uint2 u;
          u.x = pk2bf(S[t][g][0], S[t][g][1]);
          u.y = pk2bf(S[t][g][2], S[t][g][3]);
          *(uint2*)(Pw + (g * 16 + fc) * LDP + t * 16 + fq * 4) = u;
        }
      bf16x8 pb[2][2];
#pragma unroll
      for (int g = 0; g < 2; g++)
#pragma unroll
        for (int s = 0; s < 2; s++)
          pb[g][s] = *(const bf16x8*)(Pw + (g * 16 + fc) * LDP + s * 32 + fq * 8);
      // rescale O, then O^T += V^T x P
#pragma unroll
      for (int dt = 0; dt < 4; dt++)
#pragma unroll
        for (int g = 0; g < 2; g++)
#pragma unroll
          for (int r = 0; r < 4; r++) O[dt][g][r] *= alpha[g];
#pragma unroll
      for (int dt = 0; dt < 4; dt++) {
        bf16x8 va0 = *(const bf16x8*)(VTs + (dt * 16 + fc) * 64 + ((fq ^ fc7) * 8));
        bf16x8 va1 = *(const bf16x8*)(VTs + (dt * 16 + fc) * 64 + (((4 + fq) ^ fc7) * 8));
#pragma unroll
        for (int g = 0; g < 2; g++) {
          O[dt][g] = __builtin_amdgcn_mfma_f32_16x16x32_bf16(va0, pb[g][0], O[dt][g], 0, 0, 0);
          O[dt][g] = __builtin_amdgcn_mfma_f32_16x16x32_bf16(va1, pb[g][1], O[dt][g], 0, 0, 0);
        }
      }
    }

    // epilogue: lane holds O^T[d=dt*16+fq*4+r][q=g*16+fc]
    float inv[2] = {1.f / lsx[0], 1.f / lsx[1]};
#pragma unroll
    for (int dt = 0; dt < 4; dt++)
#pragma unroll
      for (int g = 0; g < 2; g++) {
        uint2 u;
        u.x = pk2bf(O[dt][g][0] * inv[g], O[dt][g][1] * inv[g]);
        u.y = pk2bf(O[dt][g][2] * inv[g], O[dt][g][3] * inv[g]);
        size_t row = (size_t)(b * NS) + qw + g * 16 + fc;
        *(uint2*)(outa + row * 1024 + h * 64 + dt * 16 + fq * 4) = u;
      }
    __syncthreads();  // protect Ks/VTs before next phase restages
  }
}

// ---------------- launch ----------------
// ws (bf16 elems): xb[8192*1024] | wqkv[3072*1024] | wo[1024*1024]
//                  | Q[64*2048*64] | K[64*2048*64] | VT[64*64*2048] | att[8192*1024]
extern "C" void kernel_launch(void* const* d_in, const int* in_sizes, int n_in,
                              void* d_out, int out_size, void* d_ws, size_t ws_size,
                              hipStream_t stream) {
  const float* x     = (const float*)d_in[0];
  const float* qkv_w = (const float*)d_in[1];
  const float* qkv_b = (const float*)d_in[2];
  const float* out_w = (const float*)d_in[3];
  const float* out_b = (const float*)d_in[4];

  unsigned short* xb   = (unsigned short*)d_ws;
  unsigned short* wqkv = xb + (size_t)8192 * 1024;
  unsigned short* wo   = wqkv + (size_t)3072 * 1024;
  unsigned short* Qg   = wo + (size_t)1024 * 1024;
  unsigned short* Kg   = Qg + (size_t)64 * 2048 * 64;
  unsigned short* Vg   = Kg + (size_t)64 * 2048 * 64;
  unsigned short* att  = Vg + (size_t)64 * 64 * 2048;

  cast_k<<<(2097152 + 255) / 256, 256, 0, stream>>>(x, xb, 2097152);
  cast_k<<<(786432 + 255) / 256, 256, 0, stream>>>(qkv_w, wqkv, 786432);
  cast_k<<<(262144 + 255) / 256, 256, 0, stream>>>(out_w, wo, 262144);

  gemm_bt<1><<<dim3(24, 64), 256, 0, stream>>>(xb, wqkv, qkv_b, nullptr,
                                               Qg, Kg, Vg, 8192, 3072, 1024);
  attn_k<<<dim3(16, 64), 128, 0, stream>>>(Qg, Kg, Vg, att);
  gemm_bt<0><<<dim3(8, 64), 256, 0, stream>>>(att, wo, out_b, d_out,
                                              nullptr, nullptr, nullptr,
                                              8192, 1024, 1024);
}